// Round 9
// baseline (246.457 us; speedup 1.0000x reference)
//
#include <hip/hip_runtime.h>

typedef unsigned short u16;
typedef __bf16 bf16x8 __attribute__((ext_vector_type(8)));
typedef float f32x4 __attribute__((ext_vector_type(4)));

// ---------- bf16 <-> f32 helpers (RNE) ----------
__device__ __forceinline__ u16 f2bf(float f) {
    union { float f; unsigned int u; } v; v.f = f;
    unsigned int u = v.u;
    return (u16)((u + 0x7FFFu + ((u >> 16) & 1u)) >> 16);
}

// ---------- async global->LDS, 16B per lane ----------
__device__ __forceinline__ void load_lds16(const void* g, void* l) {
    __builtin_amdgcn_global_load_lds(
        (const __attribute__((address_space(1))) unsigned int*)g,
        (__attribute__((address_space(3))) unsigned int*)l,
        16, 0, 0);
}

// ---------------------------------------------------------------
// fused prep: 0..8191 cast x fp32->bf16; 8192..11263 transpose W;
// 11264..11295 zero rowsum (8192 floats).
// ---------------------------------------------------------------
__global__ void __launch_bounds__(256) prep_kernel(
    const float4* __restrict__ X, u16* __restrict__ xb,
    const float* __restrict__ Wq, const float* __restrict__ Wk,
    const float* __restrict__ Wv,
    u16* __restrict__ Oq, u16* __restrict__ Ok, u16* __restrict__ Ov,
    float* __restrict__ rowsum) {
    __shared__ float tile[32][33];
    const int bid = blockIdx.x, tid = threadIdx.x;
    if (bid < 8192) {
        int idx = bid * 256 + tid;
        float4 v = X[idx];
        ushort4 o;
        o.x = f2bf(v.x); o.y = f2bf(v.y); o.z = f2bf(v.z); o.w = f2bf(v.w);
        *(ushort4*)(xb + (size_t)idx * 4) = o;
    } else if (bid < 11264) {
        int id = bid - 8192;
        int zz = id >> 10;
        const float* W = (zz == 0) ? Wq : (zz == 1) ? Wk : Wv;
        u16* O = (zz == 0) ? Oq : (zz == 1) ? Ok : Ov;
        int n0 = (id & 31) * 32, k0 = ((id >> 5) & 31) * 32;
        int tx = tid & 31, ty = tid >> 5;
        #pragma unroll
        for (int j = 0; j < 32; j += 8)
            tile[ty + j][tx] = W[(size_t)(k0 + ty + j) * 1024 + n0 + tx];
        __syncthreads();
        #pragma unroll
        for (int j = 0; j < 32; j += 8)
            O[(size_t)(n0 + ty + j) * 1024 + k0 + tx] = f2bf(tile[tx][ty + j]);
    } else {
        rowsum[(bid - 11264) * 256 + tid] = 0.f;
    }
}

// ---------------------------------------------------------------
// QKV GEMM: 128x128 tile, 512 threads = 8 waves (2x4), BK=64, H=2
// single-buffered LDS (32 KiB), XOR-swizzled (conflict-free). 1536
// blocks, 6x oversubscribed, XCD-clustered by mtile. R7-proven.
// z=0/1 -> Q/K row-major; z=2 -> Vt[b][d][s] store.
// ---------------------------------------------------------------
__global__ void __launch_bounds__(512) gemm_qkv(
    const u16* __restrict__ xb, const u16* __restrict__ WqT,
    const u16* __restrict__ WkT, const u16* __restrict__ WvT,
    u16* __restrict__ Q, u16* __restrict__ Kb, u16* __restrict__ Vt) {

    int L = blockIdx.x;
    int c = L & 7, t = (L >> 3) & 7, hi = L >> 6;
    int p = hi * 8 + c;
    const int z = p >> 6, mtile = p & 63, ntile = t;
    const u16* A = xb;
    const u16* B = (z == 0) ? WqT : (z == 1) ? WkT : WvT;

    __shared__ __align__(16) u16 As[2 * 128 * 32];
    __shared__ __align__(16) u16 Bs[2 * 128 * 32];

    const int tid = threadIdx.x;
    const int lane = tid & 63;
    const int wave = tid >> 6;
    const int wr = wave >> 2, wc = wave & 3;

    const int r0 = tid >> 2;
    const int kb = (((tid & 3) ^ ((r0 >> 1) & 3))) * 16;

    const char* gA = (const char*)(A + (size_t)(mtile * 128 + r0) * 1024) + kb;
    const char* gB = (const char*)(B + (size_t)(ntile * 128 + r0) * 1024) + kb;
    char* lA = (char*)As + tid * 16;
    char* lB = (char*)Bs + tid * 16;

    f32x4 acc[4][2] = {};

    const int quad = lane >> 4;
    const int l16 = lane & 15;
    const int ch = quad ^ ((l16 >> 1) & 3);
    const int aoff = (wr * 64 + l16) * 32 + ch * 8;
    const int boff = (wc * 32 + l16) * 32 + ch * 8;

    for (int kt = 0; kt < 16; ++kt) {
        load_lds16(gA,      lA);
        load_lds16(gA + 64, lA + 8192);
        load_lds16(gB,      lB);
        load_lds16(gB + 64, lB + 8192);
        gA += 128; gB += 128;
        __syncthreads();
        #pragma unroll
        for (int h = 0; h < 2; ++h) {
            const u16* ap = As + h * 4096 + aoff;
            const u16* bp = Bs + h * 4096 + boff;
            bf16x8 af[4], bfv[2];
            #pragma unroll
            for (int r = 0; r < 4; ++r) af[r] = *(const bf16x8*)(ap + r * 512);
            #pragma unroll
            for (int cc = 0; cc < 2; ++cc) bfv[cc] = *(const bf16x8*)(bp + cc * 512);
            #pragma unroll
            for (int r = 0; r < 4; ++r)
                #pragma unroll
                for (int cc = 0; cc < 2; ++cc)
                    acc[r][cc] = __builtin_amdgcn_mfma_f32_16x16x32_bf16(
                        af[r], bfv[cc], acc[r][cc], 0, 0, 0);
        }
        __syncthreads();
    }

    const int grow0 = mtile * 128 + wr * 64 + quad * 4;
    const int gcol0 = ntile * 128 + wc * 32 + l16;

    if (z < 2) {
        u16* C = z ? Kb : Q;
        #pragma unroll
        for (int r = 0; r < 4; ++r)
            #pragma unroll
            for (int cc = 0; cc < 2; ++cc)
                #pragma unroll
                for (int i = 0; i < 4; ++i)
                    C[(size_t)(grow0 + r * 16 + i) * 1024 + gcol0 + cc * 16] =
                        f2bf(acc[r][cc][i]);
    } else {
        #pragma unroll
        for (int r = 0; r < 4; ++r) {
            int m0 = grow0 + r * 16;
            int b = m0 >> 11, s0 = m0 & 2047;
            #pragma unroll
            for (int cc = 0; cc < 2; ++cc) {
                int d = gcol0 + cc * 16;
                ushort4 o;
                o.x = f2bf(acc[r][cc][0]); o.y = f2bf(acc[r][cc][1]);
                o.z = f2bf(acc[r][cc][2]); o.w = f2bf(acc[r][cc][3]);
                *(ushort4*)(Vt + (size_t)b * (1024 * 2048) + (size_t)d * 2048 + s0) = o;
            }
        }
    }
}

// ---------------------------------------------------------------
// Small-tile GEMM for scores / PV: 64x128 tile, 256 threads = 4 waves,
// each wave 64x32 (acc 8 f32x4). BK=64, H=2, LDS 24 KiB -> ~6 blocks/CU
// residency + queue depth. Same XOR swizzle (16-lane pattern identical
// -> conflict-free).
//
// MODE 1 (scores): grid 2048 (g=0..31 row-groups x 16 ntiles x 4 z),
//   dead tiles (t > g/2) early-exit; K-tiles XCD-clustered (c = t&7).
//   P~ = exp(QK^T/32 - 12) -> S, causal mask by index, rowsum atomics.
// MODE 2 (PV): grid 1024 (32 g x 8 ntiles x 4 z), kiters = g+1
//   (finer causal clip), heavy-first, Vt XCD-clustered (c = ntile).
//   O = (P~ V)/rowsum.
// ---------------------------------------------------------------
template <int MODE>
__global__ void __launch_bounds__(256) gemm_small(
    const u16* __restrict__ Q, const u16* __restrict__ Kb,
    const u16* __restrict__ Vt, u16* __restrict__ S,
    float* __restrict__ rowsum, float* __restrict__ out) {

    int g, ntile, z, kiters;
    const u16 *A, *B;

    if (MODE == 1) {
        int L = blockIdx.x;          // L = g*64 + p, p = z*16 + t -> c = t&7
        int p = L & 63;
        g = L >> 6;
        z = p >> 4;
        ntile = p & 15;
        if (ntile > (g >> 1)) return;        // dead tile (above diagonal)
        kiters = 16;
        A = Q  + (size_t)z * (2048 * 1024);
        B = Kb + (size_t)z * (2048 * 1024);
    } else {
        int L = blockIdx.x;          // L = g_idx*32 + p, p = z*8 + nt -> c = nt
        int p = L & 31;
        g = 31 - (L >> 5);                   // heavy-first
        z = p >> 3;
        ntile = p & 7;
        kiters = g + 1;
        A = S  + (size_t)z * (2048 * 2048);
        B = Vt + (size_t)z * (1024 * 2048);
    }

    const int LD = (MODE == 2) ? 2048 : 1024;

    __shared__ __align__(16) u16 As[2 * 64 * 32];    //  8 KiB
    __shared__ __align__(16) u16 Bs[2 * 128 * 32];   // 16 KiB

    const int tid = threadIdx.x;
    const int lane = tid & 63;
    const int wc = tid >> 6;                 // wave 0..3 -> n-subtile
    const int r0 = tid >> 2;                 // 0..63
    const int kb = (((tid & 3) ^ ((r0 >> 1) & 3))) * 16;

    const char* gA  = (const char*)(A + (size_t)(g * 64 + r0) * LD) + kb;
    const char* gB0 = (const char*)(B + (size_t)(ntile * 128 + r0) * LD) + kb;
    const char* gB1 = gB0 + (size_t)64 * LD * 2;

    char* lA = (char*)As + tid * 16;         // half h at +h*4096
    char* lB = (char*)Bs + tid * 16;         // half h at +h*8192; rows 64.. at +4096

    f32x4 acc[4][2] = {};

    const int quad = lane >> 4;
    const int l16 = lane & 15;
    const int ch = quad ^ ((l16 >> 1) & 3);
    const int aoff = l16 * 32 + ch * 8;                  // A rows l16 + 16r
    const int boff = (wc * 32 + l16) * 32 + ch * 8;      // B rows wc*32 + l16 + 16c

    for (int kt = 0; kt < kiters; ++kt) {
        #pragma unroll
        for (int h = 0; h < 2; ++h) {
            load_lds16(gA  + h * 64, lA + h * 4096);
            load_lds16(gB0 + h * 64, lB + h * 8192);
            load_lds16(gB1 + h * 64, lB + h * 8192 + 4096);
        }
        gA += 128; gB0 += 128; gB1 += 128;
        __syncthreads();
        #pragma unroll
        for (int h = 0; h < 2; ++h) {
            const u16* ap = As + h * 2048 + aoff;
            const u16* bp = Bs + h * 4096 + boff;
            bf16x8 af[4], bfv[2];
            #pragma unroll
            for (int r = 0; r < 4; ++r) af[r] = *(const bf16x8*)(ap + r * 512);
            #pragma unroll
            for (int cc = 0; cc < 2; ++cc) bfv[cc] = *(const bf16x8*)(bp + cc * 512);
            #pragma unroll
            for (int r = 0; r < 4; ++r)
                #pragma unroll
                for (int cc = 0; cc < 2; ++cc)
                    acc[r][cc] = __builtin_amdgcn_mfma_f32_16x16x32_bf16(
                        af[r], bfv[cc], acc[r][cc], 0, 0, 0);
        }
        __syncthreads();
    }

    // epilogue — C/D layout: col = lane&15, row = (lane>>4)*4 + reg
    const int grow0 = g * 64 + quad * 4;
    const int gcol0 = ntile * 128 + wc * 32 + l16;

    if (MODE == 1) {
        u16* C = S + (size_t)z * (2048 * 2048);
        float* rs = rowsum + z * 2048;
        float rsum[4][4];
        #pragma unroll
        for (int r = 0; r < 4; ++r)
            #pragma unroll
            for (int i = 0; i < 4; ++i) rsum[r][i] = 0.f;
        #pragma unroll
        for (int r = 0; r < 4; ++r)
            #pragma unroll
            for (int cc = 0; cc < 2; ++cc)
                #pragma unroll
                for (int i = 0; i < 4; ++i) {
                    int grow = grow0 + r * 16 + i;
                    int gcol = gcol0 + cc * 16;
                    float e = (gcol <= grow)
                                  ? __expf(acc[r][cc][i] * 0.03125f - 12.0f)
                                  : 0.f;
                    C[(size_t)grow * 2048 + gcol] = f2bf(e);
                    rsum[r][i] += e;
                }
        #pragma unroll
        for (int r = 0; r < 4; ++r)
            #pragma unroll
            for (int i = 0; i < 4; ++i) {
                float s = rsum[r][i];
                s += __shfl_xor(s, 1, 64);
                s += __shfl_xor(s, 2, 64);
                s += __shfl_xor(s, 4, 64);
                s += __shfl_xor(s, 8, 64);
                if (l16 == 0)
                    atomicAdd(&rs[grow0 + r * 16 + i], s);
            }
    } else {
        const float* rs = rowsum + z * 2048;
        float* C = out + (size_t)z * (2048 * 1024);
        #pragma unroll
        for (int r = 0; r < 4; ++r)
            #pragma unroll
            for (int i = 0; i < 4; ++i) {
                int grow = grow0 + r * 16 + i;
                float inv = 1.0f / rs[grow];
                #pragma unroll
                for (int cc = 0; cc < 2; ++cc)
                    C[(size_t)grow * 1024 + gcol0 + cc * 16] = acc[r][cc][i] * inv;
            }
    }
}

// ---------------------------------------------------------------
// launch
// ---------------------------------------------------------------
extern "C" void kernel_launch(void* const* d_in, const int* in_sizes, int n_in,
                              void* d_out, int out_size, void* d_ws, size_t ws_size,
                              hipStream_t stream) {
    const float* x  = (const float*)d_in[0];
    const float* Wq = (const float*)d_in[1];
    const float* Wk = (const float*)d_in[2];
    const float* Wv = (const float*)d_in[3];
    float* out = (float*)d_out;
    char* ws = (char*)d_ws;
    const size_t Mi = 1u << 20;

    u16* xb  = (u16*)(ws);               // [8192][1024] bf16  16 MiB
    u16* WqT = (u16*)(ws + 16 * Mi);     // [1024][1024] bf16   2 MiB
    u16* WkT = (u16*)(ws + 18 * Mi);
    u16* WvT = (u16*)(ws + 20 * Mi);
    u16* Q   = (u16*)(ws + 22 * Mi);     // [8192][1024] bf16  16 MiB
    u16* Kb  = (u16*)(ws + 38 * Mi);
    u16* Vt  = (u16*)(ws + 54 * Mi);     // [4][1024][2048] bf16 16 MiB
    u16* S   = (u16*)(ws + 70 * Mi);     // [4][2048][2048] bf16 32 MiB (P~)
    float* rowsum = (float*)(ws + 102 * Mi);  // [4][2048] fp32

    // prep: cast x + transpose W + zero rowsum
    prep_kernel<<<11296, 256, 0, stream>>>(
        (const float4*)x, xb, Wq, Wk, Wv, WqT, WkT, WvT, rowsum);

    // QKV projections (z: 0=Q, 1=K, 2=Vt), 128x128, 6x oversubscribed
    gemm_qkv<<<1536, 512, 0, stream>>>(xb, WqT, WkT, WvT, Q, Kb, Vt);

    // P~ = exp(QK^T/32 - 12) + rowsum; 64x128 tiles, 1088 live blocks
    gemm_small<1><<<2048, 256, 0, stream>>>(Q, Kb, Vt, S, rowsum, out);

    // O = (P~ V)/rowsum; 64x128 tiles, 1024 blocks, heavy-first
    gemm_small<2><<<1024, 256, 0, stream>>>(Q, Kb, Vt, S, rowsum, out);
}

// Round 10
// 225.114 us; speedup vs baseline: 1.0948x; 1.0948x over previous
//
#include <hip/hip_runtime.h>

typedef unsigned short u16;
typedef __bf16 bf16x8 __attribute__((ext_vector_type(8)));
typedef float f32x4 __attribute__((ext_vector_type(4)));

// ---------- bf16 <-> f32 helpers (RNE) ----------
__device__ __forceinline__ u16 f2bf(float f) {
    union { float f; unsigned int u; } v; v.f = f;
    unsigned int u = v.u;
    return (u16)((u + 0x7FFFu + ((u >> 16) & 1u)) >> 16);
}

// ---------- async global->LDS, 16B per lane ----------
__device__ __forceinline__ void load_lds16(const void* g, void* l) {
    __builtin_amdgcn_global_load_lds(
        (const __attribute__((address_space(1))) unsigned int*)g,
        (__attribute__((address_space(3))) unsigned int*)l,
        16, 0, 0);
}

// ---------------------------------------------------------------
// fused prep: 0..8191 cast x fp32->bf16; 8192..11263 transpose W;
// 11264..11295 zero rowsum (8192 floats).
// ---------------------------------------------------------------
__global__ void __launch_bounds__(256) prep_kernel(
    const float4* __restrict__ X, u16* __restrict__ xb,
    const float* __restrict__ Wq, const float* __restrict__ Wk,
    const float* __restrict__ Wv,
    u16* __restrict__ Oq, u16* __restrict__ Ok, u16* __restrict__ Ov,
    float* __restrict__ rowsum) {
    __shared__ float tile[32][33];
    const int bid = blockIdx.x, tid = threadIdx.x;
    if (bid < 8192) {
        int idx = bid * 256 + tid;
        float4 v = X[idx];
        ushort4 o;
        o.x = f2bf(v.x); o.y = f2bf(v.y); o.z = f2bf(v.z); o.w = f2bf(v.w);
        *(ushort4*)(xb + (size_t)idx * 4) = o;
    } else if (bid < 11264) {
        int id = bid - 8192;
        int zz = id >> 10;
        const float* W = (zz == 0) ? Wq : (zz == 1) ? Wk : Wv;
        u16* O = (zz == 0) ? Oq : (zz == 1) ? Ok : Ov;
        int n0 = (id & 31) * 32, k0 = ((id >> 5) & 31) * 32;
        int tx = tid & 31, ty = tid >> 5;
        #pragma unroll
        for (int j = 0; j < 32; j += 8)
            tile[ty + j][tx] = W[(size_t)(k0 + ty + j) * 1024 + n0 + tx];
        __syncthreads();
        #pragma unroll
        for (int j = 0; j < 32; j += 8)
            O[(size_t)(n0 + ty + j) * 1024 + k0 + tx] = f2bf(tile[tx][ty + j]);
    } else {
        rowsum[(bid - 11264) * 256 + tid] = 0.f;
    }
}

// ---------------------------------------------------------------
// QKV GEMM: 128x128 tile, 512 threads = 8 waves (2x4), BK=64, H=2
// single-buffered LDS (32 KiB), XOR-swizzled (conflict-free). 1536
// blocks, 6x oversubscribed, XCD-clustered by mtile. R7-proven.
// ---------------------------------------------------------------
__global__ void __launch_bounds__(512) gemm_qkv(
    const u16* __restrict__ xb, const u16* __restrict__ WqT,
    const u16* __restrict__ WkT, const u16* __restrict__ WvT,
    u16* __restrict__ Q, u16* __restrict__ Kb, u16* __restrict__ Vt) {

    int L = blockIdx.x;
    int c = L & 7, t = (L >> 3) & 7, hi = L >> 6;
    int p = hi * 8 + c;
    const int z = p >> 6, mtile = p & 63, ntile = t;
    const u16* A = xb;
    const u16* B = (z == 0) ? WqT : (z == 1) ? WkT : WvT;

    __shared__ __align__(16) u16 As[2 * 128 * 32];
    __shared__ __align__(16) u16 Bs[2 * 128 * 32];

    const int tid = threadIdx.x;
    const int lane = tid & 63;
    const int wave = tid >> 6;
    const int wr = wave >> 2, wc = wave & 3;

    const int r0 = tid >> 2;
    const int kb = (((tid & 3) ^ ((r0 >> 1) & 3))) * 16;

    const char* gA = (const char*)(A + (size_t)(mtile * 128 + r0) * 1024) + kb;
    const char* gB = (const char*)(B + (size_t)(ntile * 128 + r0) * 1024) + kb;
    char* lA = (char*)As + tid * 16;
    char* lB = (char*)Bs + tid * 16;

    f32x4 acc[4][2] = {};

    const int quad = lane >> 4;
    const int l16 = lane & 15;
    const int ch = quad ^ ((l16 >> 1) & 3);
    const int aoff = (wr * 64 + l16) * 32 + ch * 8;
    const int boff = (wc * 32 + l16) * 32 + ch * 8;

    for (int kt = 0; kt < 16; ++kt) {
        load_lds16(gA,      lA);
        load_lds16(gA + 64, lA + 8192);
        load_lds16(gB,      lB);
        load_lds16(gB + 64, lB + 8192);
        gA += 128; gB += 128;
        __syncthreads();
        #pragma unroll
        for (int h = 0; h < 2; ++h) {
            const u16* ap = As + h * 4096 + aoff;
            const u16* bp = Bs + h * 4096 + boff;
            bf16x8 af[4], bfv[2];
            #pragma unroll
            for (int r = 0; r < 4; ++r) af[r] = *(const bf16x8*)(ap + r * 512);
            #pragma unroll
            for (int cc = 0; cc < 2; ++cc) bfv[cc] = *(const bf16x8*)(bp + cc * 512);
            #pragma unroll
            for (int r = 0; r < 4; ++r)
                #pragma unroll
                for (int cc = 0; cc < 2; ++cc)
                    acc[r][cc] = __builtin_amdgcn_mfma_f32_16x16x32_bf16(
                        af[r], bfv[cc], acc[r][cc], 0, 0, 0);
        }
        __syncthreads();
    }

    const int grow0 = mtile * 128 + wr * 64 + quad * 4;
    const int gcol0 = ntile * 128 + wc * 32 + l16;

    if (z < 2) {
        u16* C = z ? Kb : Q;
        #pragma unroll
        for (int r = 0; r < 4; ++r)
            #pragma unroll
            for (int cc = 0; cc < 2; ++cc)
                #pragma unroll
                for (int i = 0; i < 4; ++i)
                    C[(size_t)(grow0 + r * 16 + i) * 1024 + gcol0 + cc * 16] =
                        f2bf(acc[r][cc][i]);
    } else {
        #pragma unroll
        for (int r = 0; r < 4; ++r) {
            int m0 = grow0 + r * 16;
            int b = m0 >> 11, s0 = m0 & 2047;
            #pragma unroll
            for (int cc = 0; cc < 2; ++cc) {
                int d = gcol0 + cc * 16;
                ushort4 o;
                o.x = f2bf(acc[r][cc][0]); o.y = f2bf(acc[r][cc][1]);
                o.z = f2bf(acc[r][cc][2]); o.w = f2bf(acc[r][cc][3]);
                *(ushort4*)(Vt + (size_t)b * (1024 * 2048) + (size_t)d * 2048 + s0) = o;
            }
        }
    }
}

// ---------------------------------------------------------------
// Scores: P~ = exp(QK^T/32 - 12) -> S, live causal tiles only,
// per-row sums via shfl+atomicAdd. 128x128 tile, 512 thr, BK=64.
// BALANCED XCD decode: cluster c handles mtiles {c, 15-c} -> exactly
// 17 tiles per XCD per z, only 2 Q-tiles per XCD. Grid 544 (= 68*8).
// ---------------------------------------------------------------
__global__ void __launch_bounds__(512) gemm_scores(
    const u16* __restrict__ Q, const u16* __restrict__ Kb,
    u16* __restrict__ S, float* __restrict__ rowsum) {

    const int L = blockIdx.x;
    const int c = L & 7;
    const int q = L >> 3;          // 0..67
    const int z = q / 17;
    const int j = q - z * 17;      // 0..16
    const int mtile = (j <= c) ? c : 15 - c;
    const int ntile = (j <= c) ? j : j - c - 1;

    const u16* A = Q  + (size_t)z * (2048 * 1024);
    const u16* B = Kb + (size_t)z * (2048 * 1024);

    __shared__ __align__(16) u16 As[2 * 128 * 32];
    __shared__ __align__(16) u16 Bs[2 * 128 * 32];

    const int tid = threadIdx.x;
    const int lane = tid & 63;
    const int wave = tid >> 6;
    const int wr = wave >> 2, wc = wave & 3;

    const int r0 = tid >> 2;
    const int kb = (((tid & 3) ^ ((r0 >> 1) & 3))) * 16;

    const char* gA = (const char*)(A + (size_t)(mtile * 128 + r0) * 1024) + kb;
    const char* gB = (const char*)(B + (size_t)(ntile * 128 + r0) * 1024) + kb;
    char* lA = (char*)As + tid * 16;
    char* lB = (char*)Bs + tid * 16;

    f32x4 acc[4][2] = {};

    const int quad = lane >> 4;
    const int l16 = lane & 15;
    const int ch = quad ^ ((l16 >> 1) & 3);
    const int aoff = (wr * 64 + l16) * 32 + ch * 8;
    const int boff = (wc * 32 + l16) * 32 + ch * 8;

    for (int kt = 0; kt < 16; ++kt) {
        load_lds16(gA,      lA);
        load_lds16(gA + 64, lA + 8192);
        load_lds16(gB,      lB);
        load_lds16(gB + 64, lB + 8192);
        gA += 128; gB += 128;
        __syncthreads();
        #pragma unroll
        for (int h = 0; h < 2; ++h) {
            const u16* ap = As + h * 4096 + aoff;
            const u16* bp = Bs + h * 4096 + boff;
            bf16x8 af[4], bfv[2];
            #pragma unroll
            for (int r = 0; r < 4; ++r) af[r] = *(const bf16x8*)(ap + r * 512);
            #pragma unroll
            for (int cc = 0; cc < 2; ++cc) bfv[cc] = *(const bf16x8*)(bp + cc * 512);
            #pragma unroll
            for (int r = 0; r < 4; ++r)
                #pragma unroll
                for (int cc = 0; cc < 2; ++cc)
                    acc[r][cc] = __builtin_amdgcn_mfma_f32_16x16x32_bf16(
                        af[r], bfv[cc], acc[r][cc], 0, 0, 0);
        }
        __syncthreads();
    }

    const int grow0 = mtile * 128 + wr * 64 + quad * 4;
    const int gcol0 = ntile * 128 + wc * 32 + l16;

    u16* C = S + (size_t)z * (2048 * 2048);
    float* rs = rowsum + z * 2048;
    const bool diag = (ntile == mtile);
    float rsum[4][4];
    #pragma unroll
    for (int r = 0; r < 4; ++r)
        #pragma unroll
        for (int i = 0; i < 4; ++i) rsum[r][i] = 0.f;
    #pragma unroll
    for (int r = 0; r < 4; ++r)
        #pragma unroll
        for (int cc = 0; cc < 2; ++cc)
            #pragma unroll
            for (int i = 0; i < 4; ++i) {
                int grow = grow0 + r * 16 + i;
                int gcol = gcol0 + cc * 16;
                float e = 0.f;
                if (!diag || gcol <= grow)
                    e = __expf(acc[r][cc][i] * 0.03125f - 12.0f);
                C[(size_t)grow * 2048 + gcol] = f2bf(e);
                rsum[r][i] += e;
            }
    #pragma unroll
    for (int r = 0; r < 4; ++r)
        #pragma unroll
        for (int i = 0; i < 4; ++i) {
            float s = rsum[r][i];
            s += __shfl_xor(s, 1, 64);
            s += __shfl_xor(s, 2, 64);
            s += __shfl_xor(s, 4, 64);
            s += __shfl_xor(s, 8, 64);
            if (l16 == 0)
                atomicAdd(&rs[grow0 + r * 16 + i], s);
        }
}

// ---------------------------------------------------------------
// PV: O = (P~ V)/rowsum. 128x128 tile, 512 thr, BK=64. Each block
// computes TWO tiles (mtile = 15-mp then mp) -> exactly 34 kiters per
// block; 256 equal blocks = ~1/CU, perfectly balanced. Vt XCD-local
// (cluster by ntile).
// ---------------------------------------------------------------
__global__ void __launch_bounds__(512) gemm_pv(
    const u16* __restrict__ S, const u16* __restrict__ Vt,
    const float* __restrict__ rowsum, float* __restrict__ out) {

    const int L = blockIdx.x;            // 256 blocks
    const int ntile = L & 7;             // XCD cluster -> Vt L2-local
    const int x = L >> 3;                // 0..31
    const int z = x & 3;
    const int mp = x >> 2;               // 0..7

    const u16* Abase = S  + (size_t)z * (2048 * 2048);
    const u16* B     = Vt + (size_t)z * (1024 * 2048);
    const float* rs  = rowsum + z * 2048;
    float* C = out + (size_t)z * (2048 * 1024);

    __shared__ __align__(16) u16 As[2 * 128 * 32];
    __shared__ __align__(16) u16 Bs[2 * 128 * 32];

    const int tid = threadIdx.x;
    const int lane = tid & 63;
    const int wave = tid >> 6;
    const int wr = wave >> 2, wc = wave & 3;

    const int r0 = tid >> 2;
    const int kb = (((tid & 3) ^ ((r0 >> 1) & 3))) * 16;

    char* lA = (char*)As + tid * 16;
    char* lB = (char*)Bs + tid * 16;

    const int quad = lane >> 4;
    const int l16 = lane & 15;
    const int ch = quad ^ ((l16 >> 1) & 3);
    const int aoff = (wr * 64 + l16) * 32 + ch * 8;
    const int boff = (wc * 32 + l16) * 32 + ch * 8;

    #pragma unroll
    for (int ti = 0; ti < 2; ++ti) {
        const int mtile = ti ? mp : 15 - mp;
        const int kiters = (mtile + 1) * 2;

        const char* gA = (const char*)(Abase + (size_t)(mtile * 128 + r0) * 2048) + kb;
        const char* gB = (const char*)(B + (size_t)(ntile * 128 + r0) * 2048) + kb;

        f32x4 acc[4][2] = {};

        for (int kt = 0; kt < kiters; ++kt) {
            load_lds16(gA,      lA);
            load_lds16(gA + 64, lA + 8192);
            load_lds16(gB,      lB);
            load_lds16(gB + 64, lB + 8192);
            gA += 128; gB += 128;
            __syncthreads();
            #pragma unroll
            for (int h = 0; h < 2; ++h) {
                const u16* ap = As + h * 4096 + aoff;
                const u16* bp = Bs + h * 4096 + boff;
                bf16x8 af[4], bfv[2];
                #pragma unroll
                for (int r = 0; r < 4; ++r) af[r] = *(const bf16x8*)(ap + r * 512);
                #pragma unroll
                for (int cc = 0; cc < 2; ++cc) bfv[cc] = *(const bf16x8*)(bp + cc * 512);
                #pragma unroll
                for (int r = 0; r < 4; ++r)
                    #pragma unroll
                    for (int cc = 0; cc < 2; ++cc)
                        acc[r][cc] = __builtin_amdgcn_mfma_f32_16x16x32_bf16(
                            af[r], bfv[cc], acc[r][cc], 0, 0, 0);
            }
            __syncthreads();
        }

        const int grow0 = mtile * 128 + wr * 64 + quad * 4;
        const int gcol0 = ntile * 128 + wc * 32 + l16;
        #pragma unroll
        for (int r = 0; r < 4; ++r)
            #pragma unroll
            for (int i = 0; i < 4; ++i) {
                int grow = grow0 + r * 16 + i;
                float inv = 1.0f / rs[grow];
                #pragma unroll
                for (int cc = 0; cc < 2; ++cc)
                    C[(size_t)grow * 1024 + gcol0 + cc * 16] = acc[r][cc][i] * inv;
            }
    }
}

// ---------------------------------------------------------------
// launch
// ---------------------------------------------------------------
extern "C" void kernel_launch(void* const* d_in, const int* in_sizes, int n_in,
                              void* d_out, int out_size, void* d_ws, size_t ws_size,
                              hipStream_t stream) {
    const float* x  = (const float*)d_in[0];
    const float* Wq = (const float*)d_in[1];
    const float* Wk = (const float*)d_in[2];
    const float* Wv = (const float*)d_in[3];
    float* out = (float*)d_out;
    char* ws = (char*)d_ws;
    const size_t Mi = 1u << 20;

    u16* xb  = (u16*)(ws);               // [8192][1024] bf16  16 MiB
    u16* WqT = (u16*)(ws + 16 * Mi);     // [1024][1024] bf16   2 MiB
    u16* WkT = (u16*)(ws + 18 * Mi);
    u16* WvT = (u16*)(ws + 20 * Mi);
    u16* Q   = (u16*)(ws + 22 * Mi);     // [8192][1024] bf16  16 MiB
    u16* Kb  = (u16*)(ws + 38 * Mi);
    u16* Vt  = (u16*)(ws + 54 * Mi);     // [4][1024][2048] bf16 16 MiB
    u16* S   = (u16*)(ws + 70 * Mi);     // [4][2048][2048] bf16 32 MiB (P~)
    float* rowsum = (float*)(ws + 102 * Mi);  // [4][2048] fp32

    // prep: cast x + transpose W + zero rowsum
    prep_kernel<<<11296, 256, 0, stream>>>(
        (const float4*)x, xb, Wq, Wk, Wv, WqT, WkT, WvT, rowsum);

    // QKV projections (z: 0=Q, 1=K, 2=Vt), 128x128, 6x oversubscribed
    gemm_qkv<<<1536, 512, 0, stream>>>(xb, WqT, WkT, WvT, Q, Kb, Vt);

    // P~ = exp(QK^T/32 - 12) + rowsum; XCD-balanced causal tiles (544)
    gemm_scores<<<544, 512, 0, stream>>>(Q, Kb, S, rowsum);

    // O = (P~ V)/rowsum; 256 equal blocks (paired mtiles, 34 kiters each)
    gemm_pv<<<256, 512, 0, stream>>>(S, Vt, rowsum, out);
}